// Round 4
// baseline (435.108 us; speedup 1.0000x reference)
//
#include <hip/hip_runtime.h>

#define SROW 132   // padded fp32 row stride for S tiles in LDS

typedef _Float16 half8 __attribute__((ext_vector_type(8)));
typedef float f32x4 __attribute__((ext_vector_type(4)));

// v3: transpose-free MFMA formulation.
// R = Sigma * S^T  (A-frag = Sigma rows: per-lane k-contiguous -> DIRECT global
// float4 loads, no LDS staging, no scatter; B-frag = S rows from LDS).
// score[p] = -sum_k S[p,k] * R[k,p]  via per-lane dot + hl-butterfly.
// Wave w owns Sigma rows [32w,32w+32) -> Sigma read exactly once per block,
// fully vectorized, ZERO barriers in the main loop (waves free-run).
// fp16 split (x = hi + lo): acc = AH*BH + AL*BH + AH*BL (drop lo*lo).

__global__ __launch_bounds__(256, 3)
void quadform_softmax(const float* __restrict__ color,
                      const float* __restrict__ mew,
                      const float* __restrict__ sigma,
                      float* __restrict__ out) {
  __shared__ __align__(16) float s_all[4 * 16 * SROW];   // 33792 B: shifted S, all 64 p-rows
  __shared__ float scores_part[4][64];                   // per-wave score contributions

  const int tid  = threadIdx.x;
  const int wv   = tid >> 6;
  const int lane = tid & 63;
  const int hl   = lane >> 4;   // fragment k-group
  const int rl   = lane & 15;   // fragment row/col within tile
  const int m    = blockIdx.x;

  float* sw = &s_all[wv * (16 * SROW)];
  const float4* sig4 = reinterpret_cast<const float4*>(sigma + (size_t)m * 16384);

  // A-frag source: Sigma[32wv + 16kt + rl][32q + 8hl .. +8) -> two float4
  const int arow0 = 32 * wv + rl;   // kt=0 row; kt=1 adds 16

#define SIG_ISSUE(Q, PA, PB, PC, PD) do {                         \
    PA = sig4[(arow0)      * 32 + 8 * (Q) + 2 * hl];              \
    PB = sig4[(arow0)      * 32 + 8 * (Q) + 2 * hl + 1];          \
    PC = sig4[(arow0 + 16) * 32 + 8 * (Q) + 2 * hl];              \
    PD = sig4[(arow0 + 16) * 32 + 8 * (Q) + 2 * hl + 1];          \
  } while (0)

  float4 P00, P01, P10, P11, N00, N01, N10, N11;
  SIG_ISSUE(0, P00, P01, P10, P11);   // chunk-0 loads in flight during staging

  // ---- stage shifted rows [16wv,16wv+16) into this wave's S segment ----
  {
    const int hh = lane >> 5;
    const int q  = lane & 31;
    const float4* c4 = reinterpret_cast<const float4*>(color + (size_t)m * 8192)
                       + (size_t)(16 * wv) * 32;
    const float4 mw = reinterpret_cast<const float4*>(mew + (size_t)m * 128)[q];
#pragma unroll
    for (int r = 0; r < 8; ++r) {
      const int row = hh + 2 * r;
      float4 v = c4[row * 32 + q];
      v.x -= mw.x; v.y -= mw.y; v.z -= mw.z; v.w -= mw.w;
      *reinterpret_cast<float4*>(&sw[row * SROW + 4 * q]) = v;
    }
  }
  __syncthreads();   // B-frags read ALL waves' segments

#define CV(H, L, I, X) do { _Float16 t_ = (_Float16)(X);          \
    H[I] = t_; L[I] = (_Float16)((X) - (float)t_); } while (0)

  // B-frag: S[16n + rl][32q + 8hl + j], j=0..7 (contiguous in LDS row)
#define B_BUILD(Q, N, BH, BL) do {                                        \
    const float* sb_ = &s_all[(N) * (16 * SROW) + rl * SROW               \
                              + 32 * (Q) + 8 * hl];                       \
    float4 b0_ = *reinterpret_cast<const float4*>(sb_);                   \
    float4 b1_ = *reinterpret_cast<const float4*>(sb_ + 4);               \
    CV(BH, BL, 0, b0_.x); CV(BH, BL, 1, b0_.y);                           \
    CV(BH, BL, 2, b0_.z); CV(BH, BL, 3, b0_.w);                           \
    CV(BH, BL, 4, b1_.x); CV(BH, BL, 5, b1_.y);                           \
    CV(BH, BL, 6, b1_.z); CV(BH, BL, 7, b1_.w);                           \
  } while (0)

#define A_CONV(F0, F1, AH, AL) do {                                       \
    CV(AH, AL, 0, (F0).x); CV(AH, AL, 1, (F0).y);                         \
    CV(AH, AL, 2, (F0).z); CV(AH, AL, 3, (F0).w);                         \
    CV(AH, AL, 4, (F1).x); CV(AH, AL, 5, (F1).y);                         \
    CV(AH, AL, 6, (F1).z); CV(AH, AL, 7, (F1).w);                         \
  } while (0)

  f32x4 acc[8];   // acc[kt*4 + n]; indices compile-time after unroll
#pragma unroll
  for (int t = 0; t < 8; ++t) acc[t] = (f32x4){0.f, 0.f, 0.f, 0.f};

#define MT3(I, AH, AL, BH, BL) do {                                             \
    acc[I] = __builtin_amdgcn_mfma_f32_16x16x32_f16(AH, BH, acc[I], 0, 0, 0);   \
    acc[I] = __builtin_amdgcn_mfma_f32_16x16x32_f16(AL, BH, acc[I], 0, 0, 0);   \
    acc[I] = __builtin_amdgcn_mfma_f32_16x16x32_f16(AH, BL, acc[I], 0, 0, 0);   \
  } while (0)

#define CHUNK(Q, PA, PB, PC, PD, QN, NA, NB, NC, ND, DO_PRE)          \
  {                                                                   \
    if (DO_PRE) { SIG_ISSUE(QN, NA, NB, NC, ND); }                    \
    half8 bh0, bl0, bh1, bl1, bh2, bl2, bh3, bl3;                     \
    B_BUILD(Q, 0, bh0, bl0); B_BUILD(Q, 1, bh1, bl1);                 \
    B_BUILD(Q, 2, bh2, bl2); B_BUILD(Q, 3, bh3, bl3);                 \
    half8 ah0, al0, ah1, al1;                                         \
    A_CONV(PA, PB, ah0, al0); A_CONV(PC, PD, ah1, al1);               \
    MT3(0, ah0, al0, bh0, bl0); MT3(1, ah0, al0, bh1, bl1);           \
    MT3(2, ah0, al0, bh2, bl2); MT3(3, ah0, al0, bh3, bl3);           \
    MT3(4, ah1, al1, bh0, bl0); MT3(5, ah1, al1, bh1, bl1);           \
    MT3(6, ah1, al1, bh2, bl2); MT3(7, ah1, al1, bh3, bl3);           \
  }

  CHUNK(0, P00, P01, P10, P11, 1, N00, N01, N10, N11, 1)
  CHUNK(1, N00, N01, N10, N11, 2, P00, P01, P10, P11, 1)
  CHUNK(2, P00, P01, P10, P11, 3, N00, N01, N10, N11, 1)
  CHUNK(3, N00, N01, N10, N11, 0, P00, P01, P10, P11, 0)

  // ---- epilogue ----
  // D layout: R[32wv + 16kt + 4hl + r][16n + rl] in acc[kt*4+n][r]
  // part_n = sum_{kt,r} S[16n+rl][32wv+16kt+4hl+r] * acc[kt*4+n][r]
#define DOT4(A, S) ((A)[0]*(S).x + (A)[1]*(S).y + (A)[2]*(S).z + (A)[3]*(S).w)

  float part[4];
#pragma unroll
  for (int n = 0; n < 4; ++n) {
    const float* se = &s_all[n * (16 * SROW) + rl * SROW + 32 * wv + 4 * hl];
    float4 s0 = *reinterpret_cast<const float4*>(se);        // kt=0
    float4 s1 = *reinterpret_cast<const float4*>(se + 16);   // kt=1
    part[n] = DOT4(acc[n], s0) + DOT4(acc[4 + n], s1);
  }
#pragma unroll
  for (int n = 0; n < 4; ++n) {
    part[n] += __shfl_xor(part[n], 16, 64);   // sum over hl bit0
    part[n] += __shfl_xor(part[n], 32, 64);   // sum over hl bit1
  }
  // lane = 16*hl + rl: lane stores part[hl] -> scores_part[wv][p=lane]
  float myp = (hl == 0) ? part[0] : (hl == 1) ? part[1]
            : (hl == 2) ? part[2] : part[3];
  scores_part[wv][lane] = myp;
  __syncthreads();

  // ---- softmax over the 64 scores (single wave) ----
  if (tid < 64) {
    float sc = -(scores_part[0][tid] + scores_part[1][tid]
               + scores_part[2][tid] + scores_part[3][tid]);
    float mx = sc;
#pragma unroll
    for (int off = 1; off < 64; off <<= 1) mx = fmaxf(mx, __shfl_xor(mx, off, 64));
    float e = __expf(sc - mx);
    float s = e;
#pragma unroll
    for (int off = 1; off < 64; off <<= 1) s += __shfl_xor(s, off, 64);
    out[(size_t)m * 64 + tid] = e / s;
  }
}

extern "C" void kernel_launch(void* const* d_in, const int* in_sizes, int n_in,
                              void* d_out, int out_size, void* d_ws, size_t ws_size,
                              hipStream_t stream) {
  const float* color = (const float*)d_in[0];   // (M,64,128) fp32
  const float* mew   = (const float*)d_in[1];   // (M,128)    fp32
  const float* sigma = (const float*)d_in[2];   // (M,128,128) fp32
  float* out = (float*)d_out;                   // (M,64) fp32
  const int M = in_sizes[1] / 128;
  quadform_softmax<<<M, 256, 0, stream>>>(color, mew, sigma, out);
}